// Round 6
// baseline (186.415 us; speedup 1.0000x reference)
//
#include <hip/hip_runtime.h>
#include <hip/hip_bf16.h>
#include <cfloat>
#include <climits>
#include <cstdint>

#define ALPHA 30.0f
#define KSEL 16          // threshold = sorted[:,16] (17th smallest off-diag)
#define P0 1.368f        // candidate cutoff: E[cnt]≈82, P(cnt<17)~1e-13
#define CAP 224          // per-row candidate capacity (16 sigma above mean)
#define BIGV 1e30f
#define NMAX 4096

typedef __attribute__((ext_vector_type(8))) short bf16x8;
typedef __attribute__((ext_vector_type(4))) float f32x4;

#define LDS_PTR(p) ((__attribute__((address_space(3))) uint32_t*)(p))
#define GLB_PTR(p) ((const __attribute__((address_space(1))) uint32_t*)(p))

__device__ inline float bfval(ushort u) {
    return __builtin_bit_cast(float, (uint32_t)u << 16);
}

// ---------------------------------------------------------------------------
// block reduce helpers (256 threads, 4 waves)
// ---------------------------------------------------------------------------
__device__ inline float blockReduceSumF(float v, float* s) {
    for (int off = 32; off; off >>= 1) v += __shfl_down(v, off);
    int tid = threadIdx.x, wid = tid >> 6;
    if ((tid & 63) == 0) s[wid] = v;
    __syncthreads();
    float r;
    if (tid == 0) { r = s[0] + s[1] + s[2] + s[3]; s[0] = r; }
    __syncthreads();
    r = s[0];
    __syncthreads();
    return r;
}

__device__ inline int blockReduceSumI(int v, int* s) {
    for (int off = 32; off; off >>= 1) v += __shfl_down(v, off);
    int tid = threadIdx.x, wid = tid >> 6;
    if ((tid & 63) == 0) s[wid] = v;
    __syncthreads();
    int r;
    if (tid == 0) { r = s[0] + s[1] + s[2] + s[3]; s[0] = r; }
    __syncthreads();
    r = s[0];
    __syncthreads();
    return r;
}

__device__ inline int blockReduceMinI(int v, int* s) {
    for (int off = 32; off; off >>= 1) v = min(v, __shfl_down(v, off));
    int tid = threadIdx.x, wid = tid >> 6;
    if ((tid & 63) == 0) s[wid] = v;
    __syncthreads();
    int r;
    if (tid == 0) { r = min(min(s[0], s[1]), min(s[2], s[3])); s[0] = r; }
    __syncthreads();
    r = s[0];
    __syncthreads();
    return r;
}

__device__ inline int blockReduceMaxI(int v, int* s) {
    for (int off = 32; off; off >>= 1) v = max(v, __shfl_down(v, off));
    int tid = threadIdx.x, wid = tid >> 6;
    if ((tid & 63) == 0) s[wid] = v;
    __syncthreads();
    int r;
    if (tid == 0) { r = max(max(s[0], s[1]), max(s[2], s[3])); s[0] = r; }
    __syncthreads();
    r = s[0];
    __syncthreads();
    return r;
}

// ---------------------------------------------------------------------------
// Kernel 1: fused fp32->bf16 (RNE) + per-row squared norm. One row per block.
// ---------------------------------------------------------------------------
__global__ __launch_bounds__(256) void prep_kernel(const float* __restrict__ X,
                                                   ushort* __restrict__ Xb,
                                                   float* __restrict__ sq, int D) {
    int row = blockIdx.x;
    int tid = threadIdx.x;
    const float4* xr = reinterpret_cast<const float4*>(X + (size_t)row * D);
    ushort4* xo = reinterpret_cast<ushort4*>(Xb + (size_t)row * D);
    float s = 0.f;
    for (int c = tid; c < D / 4; c += 256) {
        float4 v = xr[c];
        s += v.x * v.x + v.y * v.y + v.z * v.z + v.w * v.w;
        ushort4 o;
        uint32_t b;
        b = __builtin_bit_cast(uint32_t, v.x); o.x = (ushort)((b + 0x7FFF + ((b >> 16) & 1)) >> 16);
        b = __builtin_bit_cast(uint32_t, v.y); o.y = (ushort)((b + 0x7FFF + ((b >> 16) & 1)) >> 16);
        b = __builtin_bit_cast(uint32_t, v.z); o.z = (ushort)((b + 0x7FFF + ((b >> 16) & 1)) >> 16);
        b = __builtin_bit_cast(uint32_t, v.w); o.w = (ushort)((b + 0x7FFF + ((b >> 16) & 1)) >> 16);
        xo[c] = o;
    }
    __shared__ float sw[4];
    for (int off = 32; off; off >>= 1) s += __shfl_down(s, off);
    int wid = tid >> 6;
    if ((tid & 63) == 0) sw[wid] = s;
    __syncthreads();
    if (tid == 0) sq[row] = sw[0] + sw[1] + sw[2] + sw[3];
}

// ---------------------------------------------------------------------------
// Kernel 2: per-label two smallest indices + count (64 labels)
// ---------------------------------------------------------------------------
__global__ __launch_bounds__(256) void labelinfo_kernel(const int* __restrict__ targets,
                                                        int* __restrict__ f1,
                                                        int* __restrict__ f2,
                                                        int* __restrict__ lcnt, int N) {
    int lbl = blockIdx.x;
    int tid = threadIdx.x;
    int a1 = INT_MAX, a2 = INT_MAX, c = 0;
    for (int j = tid; j < N; j += 256) {
        if (targets[j] == lbl) {
            ++c;
            if (j < a1) { a2 = a1; a1 = j; }
            else if (j < a2) a2 = j;
        }
    }
    __shared__ int s1[4], s2[4], sc[4];
    for (int off = 32; off; off >>= 1) {
        int b1 = __shfl_down(a1, off), b2 = __shfl_down(a2, off), bc = __shfl_down(c, off);
        int m1 = min(a1, b1);
        int m2 = min(max(a1, b1), min(a2, b2));
        a1 = m1; a2 = m2; c += bc;
    }
    int wid = tid >> 6;
    if ((tid & 63) == 0) { s1[wid] = a1; s2[wid] = a2; sc[wid] = c; }
    __syncthreads();
    if (tid == 0) {
        int r1 = s1[0], r2 = s2[0], rc = sc[0];
        for (int w = 1; w < 4; ++w) {
            int m1 = min(r1, s1[w]);
            int m2 = min(max(r1, s1[w]), min(r2, s2[w]));
            r1 = m1; r2 = m2; rc += sc[w];
        }
        f1[lbl] = r1; f2[lbl] = r2; lcnt[lbl] = rc;
    }
}

// ---------------------------------------------------------------------------
// Kernel 3: bf16 MFMA GEMM, upper-triangle tiles only, NO dist matrix.
// Pushes candidates (d < P0, off-diag) to per-row lists for both (i,j),(j,i).
// ---------------------------------------------------------------------------
#define GBM 128
#define GBK 32
__global__ __launch_bounds__(256) void distgemm_mfma(const ushort* __restrict__ Xb,
                                                     const float* __restrict__ sq,
                                                     float2* __restrict__ cand,
                                                     int* __restrict__ cntArr,
                                                     int N, int D) {
    if (blockIdx.x < blockIdx.y) return;   // upper triangle only (colBase >= rowBase)
    __shared__ ushort As[GBM * GBK];
    __shared__ ushort Bs[GBM * GBK];

    int tid = threadIdx.x;
    int lane = tid & 63;
    int wave = tid >> 6;
    int waveR = wave >> 1;
    int waveC = wave & 1;

    int rowBase = blockIdx.y * GBM;
    int colBase = blockIdx.x * GBM;
    bool diag = (rowBase == colBase);

    f32x4 acc[4][4];
#pragma unroll
    for (int m = 0; m < 4; ++m)
#pragma unroll
        for (int n2 = 0; n2 < 4; ++n2) {
            f32x4 z = {0.f, 0.f, 0.f, 0.f};
            acc[m][n2] = z;
        }

    for (int k0 = 0; k0 < D; k0 += GBK) {
#pragma unroll
        for (int p = 0; p < 2; ++p) {
            int c = wave + 4 * p;
            int byteoff = c * 1024 + lane * 16;
            int r  = byteoff >> 6;
            int kk = (byteoff & 63) >> 1;
            const ushort* gA = Xb + (size_t)(rowBase + r) * D + k0 + kk;
            const ushort* gB = Xb + (size_t)(colBase + r) * D + k0 + kk;
            __builtin_amdgcn_global_load_lds(GLB_PTR(gA), LDS_PTR(As + c * 512), 16, 0, 0);
            __builtin_amdgcn_global_load_lds(GLB_PTR(gB), LDS_PTR(Bs + c * 512), 16, 0, 0);
        }
        __syncthreads();

        bf16x8 aF[4], bF[4];
        int chunk = (lane >> 4) * 8;
#pragma unroll
        for (int m = 0; m < 4; ++m) {
            int rl = waveR * 64 + m * 16 + (lane & 15);
            aF[m] = *reinterpret_cast<const bf16x8*>(&As[rl * GBK + chunk]);
        }
#pragma unroll
        for (int n2 = 0; n2 < 4; ++n2) {
            int rl = waveC * 64 + n2 * 16 + (lane & 15);
            bF[n2] = *reinterpret_cast<const bf16x8*>(&Bs[rl * GBK + chunk]);
        }
#pragma unroll
        for (int m = 0; m < 4; ++m)
#pragma unroll
            for (int n2 = 0; n2 < 4; ++n2)
                acc[m][n2] = __builtin_amdgcn_mfma_f32_16x16x32_bf16(aF[m], bF[n2], acc[m][n2], 0, 0, 0);
        __syncthreads();
    }

    // epilogue: C/D map col=lane&15, row=(lane>>4)*4+reg
    int cr = (lane >> 4) * 4;
    int cc = lane & 15;
#pragma unroll
    for (int m = 0; m < 4; ++m) {
#pragma unroll
        for (int n2 = 0; n2 < 4; ++n2) {
            int gcol = colBase + waveC * 64 + n2 * 16 + cc;
            float sqc = sq[gcol];
#pragma unroll
            for (int r = 0; r < 4; ++r) {
                int grow = rowBase + waveR * 64 + m * 16 + cr + r;
                float v = sq[grow] + sqc - 2.0f * acc[m][n2][r];
                float d = sqrtf(fmaxf(v, 1e-12f));
                if (d < P0 && grow != gcol) {
                    int p = atomicAdd(&cntArr[grow], 1);
                    if (p < CAP) {
                        float2 e; e.x = d; e.y = __builtin_bit_cast(float, gcol);
                        cand[(size_t)grow * CAP + p] = e;
                    }
                    if (!diag) {
                        int q = atomicAdd(&cntArr[gcol], 1);
                        if (q < CAP) {
                            float2 e2; e2.x = d; e2.y = __builtin_bit_cast(float, grow);
                            cand[(size_t)gcol * CAP + q] = e2;
                        }
                    }
                }
            }
        }
    }
}

// ---------------------------------------------------------------------------
// Kernel 4: per-row finalize from candidate lists. One WAVE per row (4/block).
// Exact 17th-smallest among candidates (complete set when 17<=cnt<=CAP),
// masked logit sums, inline first-positive fallback logit (bf16 dot).
// Rows with cnt outside [17,CAP] are flagged for the exact fallback kernel.
// ---------------------------------------------------------------------------
__global__ __launch_bounds__(256) void rowfinal_kernel(const float2* __restrict__ cand,
                                                       const int* __restrict__ cntArr,
                                                       const int* __restrict__ targets,
                                                       const ushort* __restrict__ Xb,
                                                       const float* __restrict__ sq,
                                                       const int* __restrict__ f1,
                                                       const int* __restrict__ f2,
                                                       const int* __restrict__ lcnt,
                                                       int* __restrict__ needFB,
                                                       float* __restrict__ rowLoss,
                                                       int N, int D) {
    __shared__ float dbuf[4][CAP];
    int tid = threadIdx.x, lane = tid & 63, w = tid >> 6;
    int row = blockIdx.x * 4 + w;
    int ti = targets[row];
    int lc = lcnt[ti];
    bool validRow = (lc >= 2) && (lc < N);
    int cnt = cntArr[row];
    bool fb = (cnt < KSEL + 1) || (cnt > CAP);
    int lim = fb ? 0 : cnt;

    // load my entries (up to 4), stage d-values to LDS
    float ed[4]; int ej[4];
#pragma unroll
    for (int s = 0; s < 4; ++s) {
        int idx = lane + s * 64;
        bool in = (!fb) && (idx < cnt);
        if (in) {
            float2 e = cand[(size_t)row * CAP + idx];
            ed[s] = e.x; ej[s] = __builtin_bit_cast(int, e.y);
            dbuf[w][idx] = e.x;
        } else { ed[s] = BIGV; ej[s] = -1; }
    }
    __syncthreads();

    // exact rank: thr = value at rank KSEL (0-based) among candidates
    int rlo[4] = {0, 0, 0, 0}, req[4] = {0, 0, 0, 0};
    for (int q = 0; q < lim; ++q) {
        float u = dbuf[w][q];
#pragma unroll
        for (int s = 0; s < 4; ++s) {
            rlo[s] += (u < ed[s]);
            req[s] += (u == ed[s]);
        }
    }
    float thrc = BIGV;
#pragma unroll
    for (int s = 0; s < 4; ++s)
        if (ej[s] >= 0 && rlo[s] <= KSEL && KSEL < rlo[s] + req[s]) thrc = fminf(thrc, ed[s]);
    for (int off = 32; off; off >>= 1) thrc = fminf(thrc, __shfl_down(thrc, off));
    float thr = __shfl(thrc, 0);

    // masked sums over candidates (below-thr set is fully contained in list)
    float posS = 0.f, negS = 0.f;
    int apb = 0;
#pragma unroll
    for (int s = 0; s < 4; ++s) {
        if (ej[s] >= 0 && ed[s] < thr) {
            bool same = (targets[ej[s]] == ti);
            float e = expf(ALPHA * (1.0f - ed[s]));
            if (same) { posS += e; apb = 1; }
            else negS += e;
        }
    }
    for (int off = 32; off; off >>= 1) {
        posS += __shfl_down(posS, off);
        negS += __shfl_down(negS, off);
        apb = max(apb, __shfl_down(apb, off));
    }

    // first-positive fallback distance (bf16 dot, fp32 accum), unconditional
    int fp = 0;
    float dot = 0.f;
    if (validRow) {
        fp = (row == f1[ti]) ? f2[ti] : f1[ti];
        const ushort* xr = Xb + (size_t)row * D;
        const ushort* xf = Xb + (size_t)fp * D;
        for (int c = lane; c < D / 4; c += 64) {
            ushort4 a = *reinterpret_cast<const ushort4*>(xr + (size_t)c * 4);
            ushort4 b = *reinterpret_cast<const ushort4*>(xf + (size_t)c * 4);
            dot += bfval(a.x) * bfval(b.x) + bfval(a.y) * bfval(b.y)
                 + bfval(a.z) * bfval(b.z) + bfval(a.w) * bfval(b.w);
        }
    }
    for (int off = 32; off; off >>= 1) dot += __shfl_down(dot, off);

    if (lane == 0) {
        if (fb) {
            needFB[row] = 1;            // fallback kernel writes rowLoss[row]
        } else if (!validRow) {
            rowLoss[row] = BIGV;
        } else {
            float fbD = sqrtf(fmaxf(sq[row] + sq[fp] - 2.0f * dot, 1e-12f));
            float posLogit = apb ? posS : expf(ALPHA * (1.0f - fbD));
            rowLoss[row] = -logf(posLogit / (posLogit + negS));
        }
    }
}

// ---------------------------------------------------------------------------
// Kernel 5: exact fallback for rows with cnt outside [17, CAP].
// Recomputes the full row (bf16 dot), exact bitwise binary-search threshold,
// then masked sums. Expected to never run on this data; correctness-only.
// ---------------------------------------------------------------------------
__global__ __launch_bounds__(256) void fallback_kernel(const ushort* __restrict__ Xb,
                                                       const float* __restrict__ sq,
                                                       const int* __restrict__ targets,
                                                       const int* __restrict__ needFB,
                                                       const int* __restrict__ f1,
                                                       const int* __restrict__ f2,
                                                       const int* __restrict__ lcnt,
                                                       float* __restrict__ rowLoss,
                                                       int N, int D) {
    int row = blockIdx.x;
    if (!needFB[row]) return;

    __shared__ float xrow[1024];
    __shared__ float rowD[NMAX];
    __shared__ float sF[4];
    __shared__ int sI[4];
    int tid = threadIdx.x;

    for (int k = tid; k < D; k += 256) xrow[k] = bfval(Xb[(size_t)row * D + k]);
    __syncthreads();

    for (int j = tid; j < N; j += 256) {
        float dot = 0.f;
        const ushort* xj = Xb + (size_t)j * D;
        for (int k = 0; k < D; ++k) dot += xrow[k] * bfval(xj[k]);
        rowD[j] = (j == row) ? BIGV
                             : sqrtf(fmaxf(sq[row] + sq[j] - 2.0f * dot, 1e-12f));
    }
    __syncthreads();

    // exact: smallest float u with count(rowD <= u) >= KSEL+1
    uint32_t lo = 0, hi = 0x40800000u;
    while (lo < hi) {
        uint32_t mid = (lo + hi) >> 1;
        float mv = __builtin_bit_cast(float, mid);
        int c = 0;
        for (int j = tid; j < N; j += 256) c += (rowD[j] <= mv);
        c = blockReduceSumI(c, sI);
        if (c >= KSEL + 1) hi = mid; else lo = mid + 1;
    }
    float thr = __builtin_bit_cast(float, hi);

    int ti = targets[row];
    int lc = lcnt[ti];
    bool validRow = (lc >= 2) && (lc < N);

    float posS = 0.f, negS = 0.f;
    int apb = 0;
    for (int j = tid; j < N; j += 256) {
        if (j == row) continue;
        float d = rowD[j];
        bool same = (targets[j] == ti);
        if (d < thr) {
            float e = expf(ALPHA * (1.0f - d));
            if (same) { posS += e; apb = 1; }
            else negS += e;
        }
    }
    posS = blockReduceSumF(posS, sF);
    negS = blockReduceSumF(negS, sF);
    apb = blockReduceMaxI(apb, sI);

    if (tid == 0) {
        if (!validRow) { rowLoss[row] = BIGV; return; }
        int fp = (row == f1[ti]) ? f2[ti] : f1[ti];
        float posLogit = apb ? posS : expf(ALPHA * (1.0f - rowD[fp]));
        rowLoss[row] = -logf(posLogit / (posLogit + negS));
    }
}

// ---------------------------------------------------------------------------
// Kernel 6: single-block reduction over rowLoss -> out[4]
// ---------------------------------------------------------------------------
__global__ __launch_bounds__(256) void reduce_kernel(const float* __restrict__ rowLoss,
                                                     float* __restrict__ out, int N) {
    __shared__ float sF[4];
    __shared__ int sI[4];
    int tid = threadIdx.x;
    float sumL = 0.f;
    int nValid = 0, nAcc = 0;
    for (int j = tid; j < N; j += 256) {
        float L = rowLoss[j];
        if (L != BIGV) {
            sumL += L;
            ++nValid;
            if (L < 0.6f) ++nAcc;
        }
    }
    sumL = blockReduceSumF(sumL, sF);
    nValid = blockReduceSumI(nValid, sI);
    nAcc = blockReduceSumI(nAcc, sI);
    if (tid == 0) {
        out[0] = (nValid > 0) ? sumL / (float)nValid : 0.f;
        out[1] = (float)nAcc / (float)N;
        out[2] = 0.f;
        out[3] = 0.f;
    }
}

// ---------------------------------------------------------------------------
extern "C" void kernel_launch(void* const* d_in, const int* in_sizes, int n_in,
                              void* d_out, int out_size, void* d_ws, size_t ws_size,
                              hipStream_t stream) {
    const float* X = (const float*)d_in[0];
    const int* targets = (const int*)d_in[1];
    float* out = (float*)d_out;

    int N = in_sizes[1];             // 4096
    int D = in_sizes[0] / N;         // 1024

    float* sq      = (float*)d_ws;                    // N f32
    float* rowLoss = sq + N;                          // N f32
    int*   cntArr  = (int*)(rowLoss + N);             // N i32
    int*   needFB  = cntArr + N;                      // N i32
    int*   f1      = needFB + N;                      // 64 i32
    int*   f2      = f1 + 64;                         // 64 i32
    int*   lcnt    = f2 + 64;                         // 64 i32 (+pad)
    ushort* Xb     = (ushort*)(lcnt + 64 + 64);       // N*D bf16   (8 MB)
    float2* cand   = (float2*)(Xb + (size_t)N * D);   // N*CAP f2   (7.3 MB)

    hipMemsetAsync(cntArr, 0, N * sizeof(int), stream);
    hipMemsetAsync(needFB, 0, N * sizeof(int), stream);

    prep_kernel<<<N, 256, 0, stream>>>(X, Xb, sq, D);
    labelinfo_kernel<<<64, 256, 0, stream>>>(targets, f1, f2, lcnt, N);

    dim3 grid(N / GBM, N / GBM);
    distgemm_mfma<<<grid, 256, 0, stream>>>(Xb, sq, cand, cntArr, N, D);

    rowfinal_kernel<<<N / 4, 256, 0, stream>>>(cand, cntArr, targets, Xb, sq,
                                               f1, f2, lcnt, needFB, rowLoss, N, D);

    fallback_kernel<<<N, 256, 0, stream>>>(Xb, sq, targets, needFB,
                                           f1, f2, lcnt, rowLoss, N, D);

    reduce_kernel<<<1, 256, 0, stream>>>(rowLoss, out, N);
}

// Round 7
// 153.991 us; speedup vs baseline: 1.2106x; 1.2106x over previous
//
#include <hip/hip_runtime.h>
#include <hip/hip_bf16.h>
#include <cfloat>
#include <climits>
#include <cstdint>

#define ALPHA 30.0f
#define KSEL 16          // threshold = sorted[:,16] (17th smallest off-diag)
#define P0 1.368f        // candidate cutoff: E[cnt/row]≈82, P(cnt<17)~1e-13
#define P0SQ (P0 * P0)
#define CAP 224          // per-row candidate capacity
#define TCAP 1024        // per-tile candidate capacity (mean ~330)
#define BIGV 1e30f
#define NMAX 4096

typedef __attribute__((ext_vector_type(8))) short bf16x8;
typedef __attribute__((ext_vector_type(4))) float f32x4;

#define LDS_PTR(p) ((__attribute__((address_space(3))) uint32_t*)(p))
#define GLB_PTR(p) ((const __attribute__((address_space(1))) uint32_t*)(p))

__device__ inline float bfval(ushort u) {
    return __builtin_bit_cast(float, (uint32_t)u << 16);
}

// ---------------------------------------------------------------------------
// block reduce helpers (256 threads, 4 waves)
// ---------------------------------------------------------------------------
__device__ inline float blockReduceSumF(float v, float* s) {
    for (int off = 32; off; off >>= 1) v += __shfl_down(v, off);
    int tid = threadIdx.x, wid = tid >> 6;
    if ((tid & 63) == 0) s[wid] = v;
    __syncthreads();
    float r;
    if (tid == 0) { r = s[0] + s[1] + s[2] + s[3]; s[0] = r; }
    __syncthreads();
    r = s[0];
    __syncthreads();
    return r;
}

__device__ inline int blockReduceSumI(int v, int* s) {
    for (int off = 32; off; off >>= 1) v += __shfl_down(v, off);
    int tid = threadIdx.x, wid = tid >> 6;
    if ((tid & 63) == 0) s[wid] = v;
    __syncthreads();
    int r;
    if (tid == 0) { r = s[0] + s[1] + s[2] + s[3]; s[0] = r; }
    __syncthreads();
    r = s[0];
    __syncthreads();
    return r;
}

__device__ inline int blockReduceMaxI(int v, int* s) {
    for (int off = 32; off; off >>= 1) v = max(v, __shfl_down(v, off));
    int tid = threadIdx.x, wid = tid >> 6;
    if ((tid & 63) == 0) s[wid] = v;
    __syncthreads();
    int r;
    if (tid == 0) { r = max(max(s[0], s[1]), max(s[2], s[3])); s[0] = r; }
    __syncthreads();
    r = s[0];
    __syncthreads();
    return r;
}

// ---------------------------------------------------------------------------
// Kernel 1: fused fp32->bf16 (RNE) + per-row squared norm. One row per block.
// ---------------------------------------------------------------------------
__global__ __launch_bounds__(256) void prep_kernel(const float* __restrict__ X,
                                                   ushort* __restrict__ Xb,
                                                   float* __restrict__ sq, int D) {
    int row = blockIdx.x;
    int tid = threadIdx.x;
    const float4* xr = reinterpret_cast<const float4*>(X + (size_t)row * D);
    ushort4* xo = reinterpret_cast<ushort4*>(Xb + (size_t)row * D);
    float s = 0.f;
    for (int c = tid; c < D / 4; c += 256) {
        float4 v = xr[c];
        s += v.x * v.x + v.y * v.y + v.z * v.z + v.w * v.w;
        ushort4 o;
        uint32_t b;
        b = __builtin_bit_cast(uint32_t, v.x); o.x = (ushort)((b + 0x7FFF + ((b >> 16) & 1)) >> 16);
        b = __builtin_bit_cast(uint32_t, v.y); o.y = (ushort)((b + 0x7FFF + ((b >> 16) & 1)) >> 16);
        b = __builtin_bit_cast(uint32_t, v.z); o.z = (ushort)((b + 0x7FFF + ((b >> 16) & 1)) >> 16);
        b = __builtin_bit_cast(uint32_t, v.w); o.w = (ushort)((b + 0x7FFF + ((b >> 16) & 1)) >> 16);
        xo[c] = o;
    }
    __shared__ float sw[4];
    for (int off = 32; off; off >>= 1) s += __shfl_down(s, off);
    int wid = tid >> 6;
    if ((tid & 63) == 0) sw[wid] = s;
    __syncthreads();
    if (tid == 0) sq[row] = sw[0] + sw[1] + sw[2] + sw[3];
}

// ---------------------------------------------------------------------------
// Kernel 2: per-label two smallest indices + count (64 labels)
// ---------------------------------------------------------------------------
__global__ __launch_bounds__(256) void labelinfo_kernel(const int* __restrict__ targets,
                                                        int* __restrict__ f1,
                                                        int* __restrict__ f2,
                                                        int* __restrict__ lcnt, int N) {
    int lbl = blockIdx.x;
    int tid = threadIdx.x;
    int a1 = INT_MAX, a2 = INT_MAX, c = 0;
    for (int j = tid; j < N; j += 256) {
        if (targets[j] == lbl) {
            ++c;
            if (j < a1) { a2 = a1; a1 = j; }
            else if (j < a2) a2 = j;
        }
    }
    __shared__ int s1[4], s2[4], sc[4];
    for (int off = 32; off; off >>= 1) {
        int b1 = __shfl_down(a1, off), b2 = __shfl_down(a2, off), bc = __shfl_down(c, off);
        int m1 = min(a1, b1);
        int m2 = min(max(a1, b1), min(a2, b2));
        a1 = m1; a2 = m2; c += bc;
    }
    int wid = tid >> 6;
    if ((tid & 63) == 0) { s1[wid] = a1; s2[wid] = a2; sc[wid] = c; }
    __syncthreads();
    if (tid == 0) {
        int r1 = s1[0], r2 = s2[0], rc = sc[0];
        for (int w = 1; w < 4; ++w) {
            int m1 = min(r1, s1[w]);
            int m2 = min(max(r1, s1[w]), min(r2, s2[w]));
            r1 = m1; r2 = m2; rc += sc[w];
        }
        f1[lbl] = r1; f2[lbl] = r2; lcnt[lbl] = rc;
    }
}

// ---------------------------------------------------------------------------
// Kernel 3: bf16 MFMA GEMM, upper-triangle tiles, NO dist matrix, NO global
// atomics. Candidates (v < P0^2, off-diag) are ballot-compacted into an LDS
// per-tile list, then bulk-written coalesced to tileList[tileId].
// ---------------------------------------------------------------------------
#define GBM 128
#define GBK 32
__global__ __launch_bounds__(256) void distgemm_mfma(const ushort* __restrict__ Xb,
                                                     const float* __restrict__ sq,
                                                     float2* __restrict__ tileList,
                                                     int* __restrict__ tileCnt,
                                                     int* __restrict__ needFB,
                                                     int N, int D) {
    if (blockIdx.x < blockIdx.y) return;   // upper triangle only
    __shared__ ushort As[GBM * GBK];
    __shared__ ushort Bs[GBM * GBK];
    __shared__ float2 tlist[TCAP];         // 8 KB
    __shared__ int s_cnt;

    int tid = threadIdx.x;
    int lane = tid & 63;
    int wave = tid >> 6;
    int waveR = wave >> 1;
    int waveC = wave & 1;

    int rowBase = blockIdx.y * GBM;
    int colBase = blockIdx.x * GBM;

    if (tid == 0) s_cnt = 0;

    f32x4 acc[4][4];
#pragma unroll
    for (int m = 0; m < 4; ++m)
#pragma unroll
        for (int n2 = 0; n2 < 4; ++n2) {
            f32x4 z = {0.f, 0.f, 0.f, 0.f};
            acc[m][n2] = z;
        }

    for (int k0 = 0; k0 < D; k0 += GBK) {
#pragma unroll
        for (int p = 0; p < 2; ++p) {
            int c = wave + 4 * p;
            int byteoff = c * 1024 + lane * 16;
            int r  = byteoff >> 6;
            int kk = (byteoff & 63) >> 1;
            const ushort* gA = Xb + (size_t)(rowBase + r) * D + k0 + kk;
            const ushort* gB = Xb + (size_t)(colBase + r) * D + k0 + kk;
            __builtin_amdgcn_global_load_lds(GLB_PTR(gA), LDS_PTR(As + c * 512), 16, 0, 0);
            __builtin_amdgcn_global_load_lds(GLB_PTR(gB), LDS_PTR(Bs + c * 512), 16, 0, 0);
        }
        __syncthreads();

        bf16x8 aF[4], bF[4];
        int chunk = (lane >> 4) * 8;
#pragma unroll
        for (int m = 0; m < 4; ++m) {
            int rl = waveR * 64 + m * 16 + (lane & 15);
            aF[m] = *reinterpret_cast<const bf16x8*>(&As[rl * GBK + chunk]);
        }
#pragma unroll
        for (int n2 = 0; n2 < 4; ++n2) {
            int rl = waveC * 64 + n2 * 16 + (lane & 15);
            bF[n2] = *reinterpret_cast<const bf16x8*>(&Bs[rl * GBK + chunk]);
        }
#pragma unroll
        for (int m = 0; m < 4; ++m)
#pragma unroll
            for (int n2 = 0; n2 < 4; ++n2)
                acc[m][n2] = __builtin_amdgcn_mfma_f32_16x16x32_bf16(aF[m], bF[n2], acc[m][n2], 0, 0, 0);
        __syncthreads();
    }

    // epilogue: ballot-compact candidates into LDS tile list (no global atomics)
    int cr = (lane >> 4) * 4;
    int cc = lane & 15;
    unsigned long long lmask_lt = (1ull << lane) - 1ull;
#pragma unroll
    for (int m = 0; m < 4; ++m) {
#pragma unroll
        for (int n2 = 0; n2 < 4; ++n2) {
            int gcol = colBase + waveC * 64 + n2 * 16 + cc;
            float sqc = sq[gcol];
#pragma unroll
            for (int r = 0; r < 4; ++r) {
                int grow = rowBase + waveR * 64 + m * 16 + cr + r;
                float v = sq[grow] + sqc - 2.0f * acc[m][n2][r];
                bool pred = (v < P0SQ) && (grow != gcol);
                unsigned long long mask = __ballot(pred);
                if (mask) {
                    int leader = __ffsll((long long)mask) - 1;
                    int tot = __popcll(mask);
                    int base = 0;
                    if (lane == leader) base = atomicAdd(&s_cnt, tot);
                    base = __shfl(base, leader);
                    if (pred) {
                        int idx = base + __popcll(mask & lmask_lt);
                        if (idx < TCAP) {
                            float d = sqrtf(fmaxf(v, 1e-12f));
                            uint32_t pk = ((uint32_t)grow << 12) | (uint32_t)gcol;
                            float2 e; e.x = d; e.y = __builtin_bit_cast(float, pk);
                            tlist[idx] = e;
                        }
                    }
                }
            }
        }
    }
    __syncthreads();

    int cnt = s_cnt;
    int tileId = blockIdx.y * gridDim.x + blockIdx.x;
    int wr = min(cnt, TCAP);
    for (int e = tid; e < wr; e += 256)
        tileList[(size_t)tileId * TCAP + e] = tlist[e];
    if (tid == 0) tileCnt[tileId] = cnt;
    if (cnt > TCAP) {   // astronomically unlikely; exact fallback covers it
        if (tid < GBM) needFB[rowBase + tid] = 1;
        else needFB[colBase + tid - GBM] = 1;
    }
}

// ---------------------------------------------------------------------------
// Kernel 4: binning — scatter tile lists into per-row candidate lists.
// High-occupancy streaming kernel; atomic latency hidden by wave count.
// ---------------------------------------------------------------------------
__global__ __launch_bounds__(256) void bin_kernel(const float2* __restrict__ tileList,
                                                  const int* __restrict__ tileCnt,
                                                  float2* __restrict__ cand,
                                                  int* __restrict__ cntArr) {
    int bx = blockIdx.x, by = blockIdx.y;
    if (bx < by) return;
    int t = by * gridDim.x + bx;
    int cnt = min(tileCnt[t], TCAP);
    bool diag = (bx == by);
    for (int e = threadIdx.x; e < cnt; e += 256) {
        float2 v = tileList[(size_t)t * TCAP + e];
        uint32_t pk = __builtin_bit_cast(uint32_t, v.y);
        int i = (int)(pk >> 12), j = (int)(pk & 4095u);
        int p = atomicAdd(&cntArr[i], 1);
        if (p < CAP) {
            float2 e1; e1.x = v.x; e1.y = __builtin_bit_cast(float, j);
            cand[(size_t)i * CAP + p] = e1;
        }
        if (!diag) {
            int q = atomicAdd(&cntArr[j], 1);
            if (q < CAP) {
                float2 e2; e2.x = v.x; e2.y = __builtin_bit_cast(float, i);
                cand[(size_t)j * CAP + q] = e2;
            }
        }
    }
}

// ---------------------------------------------------------------------------
// Kernel 5: per-row finalize from candidate lists. One WAVE per row (4/block).
// ---------------------------------------------------------------------------
__global__ __launch_bounds__(256) void rowfinal_kernel(const float2* __restrict__ cand,
                                                       const int* __restrict__ cntArr,
                                                       const int* __restrict__ targets,
                                                       const ushort* __restrict__ Xb,
                                                       const float* __restrict__ sq,
                                                       const int* __restrict__ f1,
                                                       const int* __restrict__ f2,
                                                       const int* __restrict__ lcnt,
                                                       int* __restrict__ needFB,
                                                       float* __restrict__ rowLoss,
                                                       int N, int D) {
    __shared__ float dbuf[4][CAP];
    int tid = threadIdx.x, lane = tid & 63, w = tid >> 6;
    int row = blockIdx.x * 4 + w;
    int ti = targets[row];
    int lc = lcnt[ti];
    bool validRow = (lc >= 2) && (lc < N);
    int cnt = cntArr[row];
    bool fb = (cnt < KSEL + 1) || (cnt > CAP);
    int lim = fb ? 0 : cnt;

    float ed[4]; int ej[4];
#pragma unroll
    for (int s = 0; s < 4; ++s) {
        int idx = lane + s * 64;
        bool in = (!fb) && (idx < cnt);
        if (in) {
            float2 e = cand[(size_t)row * CAP + idx];
            ed[s] = e.x; ej[s] = __builtin_bit_cast(int, e.y);
            dbuf[w][idx] = e.x;
        } else { ed[s] = BIGV; ej[s] = -1; }
    }
    __syncthreads();

    // exact rank: thr = value at rank KSEL (0-based) among candidates
    int rlo[4] = {0, 0, 0, 0}, req[4] = {0, 0, 0, 0};
    for (int q = 0; q < lim; ++q) {
        float u = dbuf[w][q];
#pragma unroll
        for (int s = 0; s < 4; ++s) {
            rlo[s] += (u < ed[s]);
            req[s] += (u == ed[s]);
        }
    }
    float thrc = BIGV;
#pragma unroll
    for (int s = 0; s < 4; ++s)
        if (ej[s] >= 0 && rlo[s] <= KSEL && KSEL < rlo[s] + req[s]) thrc = fminf(thrc, ed[s]);
    for (int off = 32; off; off >>= 1) thrc = fminf(thrc, __shfl_down(thrc, off));
    float thr = __shfl(thrc, 0);

    // masked sums over candidates (below-thr set fully contained in list)
    float posS = 0.f, negS = 0.f;
    int apb = 0;
#pragma unroll
    for (int s = 0; s < 4; ++s) {
        if (ej[s] >= 0 && ed[s] < thr) {
            bool same = (targets[ej[s]] == ti);
            float e = expf(ALPHA * (1.0f - ed[s]));
            if (same) { posS += e; apb = 1; }
            else negS += e;
        }
    }
    for (int off = 32; off; off >>= 1) {
        posS += __shfl_down(posS, off);
        negS += __shfl_down(negS, off);
        apb = max(apb, __shfl_down(apb, off));
    }

    // first-positive fallback distance (bf16 dot, fp32 accum)
    int fp = 0;
    float dot = 0.f;
    if (validRow) {
        fp = (row == f1[ti]) ? f2[ti] : f1[ti];
        const ushort* xr = Xb + (size_t)row * D;
        const ushort* xf = Xb + (size_t)fp * D;
        for (int c = lane; c < D / 4; c += 64) {
            ushort4 a = *reinterpret_cast<const ushort4*>(xr + (size_t)c * 4);
            ushort4 b = *reinterpret_cast<const ushort4*>(xf + (size_t)c * 4);
            dot += bfval(a.x) * bfval(b.x) + bfval(a.y) * bfval(b.y)
                 + bfval(a.z) * bfval(b.z) + bfval(a.w) * bfval(b.w);
        }
    }
    for (int off = 32; off; off >>= 1) dot += __shfl_down(dot, off);

    if (lane == 0) {
        if (fb) {
            needFB[row] = 1;
        } else if (!validRow) {
            rowLoss[row] = BIGV;
        } else {
            float fbD = sqrtf(fmaxf(sq[row] + sq[fp] - 2.0f * dot, 1e-12f));
            float posLogit = apb ? posS : expf(ALPHA * (1.0f - fbD));
            rowLoss[row] = -logf(posLogit / (posLogit + negS));
        }
    }
}

// ---------------------------------------------------------------------------
// Kernel 6: exact fallback (full-row recompute). Expected zero work.
// ---------------------------------------------------------------------------
__global__ __launch_bounds__(256) void fallback_kernel(const ushort* __restrict__ Xb,
                                                       const float* __restrict__ sq,
                                                       const int* __restrict__ targets,
                                                       const int* __restrict__ needFB,
                                                       const int* __restrict__ f1,
                                                       const int* __restrict__ f2,
                                                       const int* __restrict__ lcnt,
                                                       float* __restrict__ rowLoss,
                                                       int N, int D) {
    int row = blockIdx.x;
    if (!needFB[row]) return;

    __shared__ float xrow[1024];
    __shared__ float rowD[NMAX];
    __shared__ float sF[4];
    __shared__ int sI[4];
    int tid = threadIdx.x;

    for (int k = tid; k < D; k += 256) xrow[k] = bfval(Xb[(size_t)row * D + k]);
    __syncthreads();

    for (int j = tid; j < N; j += 256) {
        float dot = 0.f;
        const ushort* xj = Xb + (size_t)j * D;
        for (int k = 0; k < D; ++k) dot += xrow[k] * bfval(xj[k]);
        rowD[j] = (j == row) ? BIGV
                             : sqrtf(fmaxf(sq[row] + sq[j] - 2.0f * dot, 1e-12f));
    }
    __syncthreads();

    uint32_t lo = 0, hi = 0x40800000u;
    while (lo < hi) {
        uint32_t mid = (lo + hi) >> 1;
        float mv = __builtin_bit_cast(float, mid);
        int c = 0;
        for (int j = tid; j < N; j += 256) c += (rowD[j] <= mv);
        c = blockReduceSumI(c, sI);
        if (c >= KSEL + 1) hi = mid; else lo = mid + 1;
    }
    float thr = __builtin_bit_cast(float, hi);

    int ti = targets[row];
    int lc = lcnt[ti];
    bool validRow = (lc >= 2) && (lc < N);

    float posS = 0.f, negS = 0.f;
    int apb = 0;
    for (int j = tid; j < N; j += 256) {
        if (j == row) continue;
        float d = rowD[j];
        bool same = (targets[j] == ti);
        if (d < thr) {
            float e = expf(ALPHA * (1.0f - d));
            if (same) { posS += e; apb = 1; }
            else negS += e;
        }
    }
    posS = blockReduceSumF(posS, sF);
    negS = blockReduceSumF(negS, sF);
    apb = blockReduceMaxI(apb, sI);

    if (tid == 0) {
        if (!validRow) { rowLoss[row] = BIGV; return; }
        int fp = (row == f1[ti]) ? f2[ti] : f1[ti];
        float posLogit = apb ? posS : expf(ALPHA * (1.0f - rowD[fp]));
        rowLoss[row] = -logf(posLogit / (posLogit + negS));
    }
}

// ---------------------------------------------------------------------------
// Kernel 7: single-block reduction over rowLoss -> out[4]
// ---------------------------------------------------------------------------
__global__ __launch_bounds__(256) void reduce_kernel(const float* __restrict__ rowLoss,
                                                     float* __restrict__ out, int N) {
    __shared__ float sF[4];
    __shared__ int sI[4];
    int tid = threadIdx.x;
    float sumL = 0.f;
    int nValid = 0, nAcc = 0;
    for (int j = tid; j < N; j += 256) {
        float L = rowLoss[j];
        if (L != BIGV) {
            sumL += L;
            ++nValid;
            if (L < 0.6f) ++nAcc;
        }
    }
    sumL = blockReduceSumF(sumL, sF);
    nValid = blockReduceSumI(nValid, sI);
    nAcc = blockReduceSumI(nAcc, sI);
    if (tid == 0) {
        out[0] = (nValid > 0) ? sumL / (float)nValid : 0.f;
        out[1] = (float)nAcc / (float)N;
        out[2] = 0.f;
        out[3] = 0.f;
    }
}

// ---------------------------------------------------------------------------
extern "C" void kernel_launch(void* const* d_in, const int* in_sizes, int n_in,
                              void* d_out, int out_size, void* d_ws, size_t ws_size,
                              hipStream_t stream) {
    const float* X = (const float*)d_in[0];
    const int* targets = (const int*)d_in[1];
    float* out = (float*)d_out;

    int N = in_sizes[1];             // 4096
    int D = in_sizes[0] / N;         // 1024
    int tiles = N / GBM;             // 32

    // 8B-aligned float2 arrays first
    float2* cand     = (float2*)d_ws;                          // N*CAP f2      (7.3 MB)
    float2* tileList = cand + (size_t)N * CAP;                 // tiles^2*TCAP  (8.4 MB)
    float*  sq       = (float*)(tileList + (size_t)tiles * tiles * TCAP);
    float*  rowLoss  = sq + N;
    int*    cntArr   = (int*)(rowLoss + N);
    int*    needFB   = cntArr + N;
    int*    tileCnt  = needFB + N;                             // tiles^2 i32
    int*    f1       = tileCnt + tiles * tiles;
    int*    f2       = f1 + 64;
    int*    lcnt     = f2 + 64;
    ushort* Xb       = (ushort*)(lcnt + 64 + 64);              // N*D bf16 (8 MB)

    hipMemsetAsync(cntArr, 0, N * sizeof(int), stream);
    hipMemsetAsync(needFB, 0, N * sizeof(int), stream);

    prep_kernel<<<N, 256, 0, stream>>>(X, Xb, sq, D);
    labelinfo_kernel<<<64, 256, 0, stream>>>(targets, f1, f2, lcnt, N);

    dim3 grid(tiles, tiles);
    distgemm_mfma<<<grid, 256, 0, stream>>>(Xb, sq, tileList, tileCnt, needFB, N, D);

    bin_kernel<<<grid, 256, 0, stream>>>(tileList, tileCnt, cand, cntArr);

    rowfinal_kernel<<<N / 4, 256, 0, stream>>>(cand, cntArr, targets, Xb, sq,
                                               f1, f2, lcnt, needFB, rowLoss, N, D);

    fallback_kernel<<<N, 256, 0, stream>>>(Xb, sq, targets, needFB,
                                           f1, f2, lcnt, rowLoss, N, D);

    reduce_kernel<<<1, 256, 0, stream>>>(rowLoss, out, N);
}

// Round 8
// 147.995 us; speedup vs baseline: 1.2596x; 1.0405x over previous
//
#include <hip/hip_runtime.h>
#include <hip/hip_bf16.h>
#include <cfloat>
#include <climits>
#include <cstdint>

#define ALPHA 30.0f
#define KSEL 16          // threshold = sorted[:,16] (17th smallest off-diag)
#define P0 1.368f        // candidate cutoff: E[cnt/row]≈82, P(cnt<17)~1e-13
#define P0SQ (P0 * P0)
#define CAP 224          // per-row candidate capacity
#define TCAP 1024        // per-tile candidate capacity (mean ~330)
#define BIGV 1e30f
#define NMAX 4096

typedef __attribute__((ext_vector_type(8))) short bf16x8;
typedef __attribute__((ext_vector_type(4))) float f32x4;

#define LDS_PTR(p) ((__attribute__((address_space(3))) uint32_t*)(p))
#define GLB_PTR(p) ((const __attribute__((address_space(1))) uint32_t*)(p))

__device__ inline float bfval(ushort u) {
    return __builtin_bit_cast(float, (uint32_t)u << 16);
}

// ---------------------------------------------------------------------------
// block reduce helpers (256 threads, 4 waves)
// ---------------------------------------------------------------------------
__device__ inline float blockReduceSumF(float v, float* s) {
    for (int off = 32; off; off >>= 1) v += __shfl_down(v, off);
    int tid = threadIdx.x, wid = tid >> 6;
    if ((tid & 63) == 0) s[wid] = v;
    __syncthreads();
    float r;
    if (tid == 0) { r = s[0] + s[1] + s[2] + s[3]; s[0] = r; }
    __syncthreads();
    r = s[0];
    __syncthreads();
    return r;
}

__device__ inline int blockReduceSumI(int v, int* s) {
    for (int off = 32; off; off >>= 1) v += __shfl_down(v, off);
    int tid = threadIdx.x, wid = tid >> 6;
    if ((tid & 63) == 0) s[wid] = v;
    __syncthreads();
    int r;
    if (tid == 0) { r = s[0] + s[1] + s[2] + s[3]; s[0] = r; }
    __syncthreads();
    r = s[0];
    __syncthreads();
    return r;
}

__device__ inline int blockReduceMaxI(int v, int* s) {
    for (int off = 32; off; off >>= 1) v = max(v, __shfl_down(v, off));
    int tid = threadIdx.x, wid = tid >> 6;
    if ((tid & 63) == 0) s[wid] = v;
    __syncthreads();
    int r;
    if (tid == 0) { r = max(max(s[0], s[1]), max(s[2], s[3])); s[0] = r; }
    __syncthreads();
    r = s[0];
    __syncthreads();
    return r;
}

// ---------------------------------------------------------------------------
// Kernel 1: fused fp32->bf16 (RNE) + per-row squared norm. One row per block.
// ---------------------------------------------------------------------------
__global__ __launch_bounds__(256) void prep_kernel(const float* __restrict__ X,
                                                   ushort* __restrict__ Xb,
                                                   float* __restrict__ sq, int D) {
    int row = blockIdx.x;
    int tid = threadIdx.x;
    const float4* xr = reinterpret_cast<const float4*>(X + (size_t)row * D);
    ushort4* xo = reinterpret_cast<ushort4*>(Xb + (size_t)row * D);
    float s = 0.f;
    for (int c = tid; c < D / 4; c += 256) {
        float4 v = xr[c];
        s += v.x * v.x + v.y * v.y + v.z * v.z + v.w * v.w;
        ushort4 o;
        uint32_t b;
        b = __builtin_bit_cast(uint32_t, v.x); o.x = (ushort)((b + 0x7FFF + ((b >> 16) & 1)) >> 16);
        b = __builtin_bit_cast(uint32_t, v.y); o.y = (ushort)((b + 0x7FFF + ((b >> 16) & 1)) >> 16);
        b = __builtin_bit_cast(uint32_t, v.z); o.z = (ushort)((b + 0x7FFF + ((b >> 16) & 1)) >> 16);
        b = __builtin_bit_cast(uint32_t, v.w); o.w = (ushort)((b + 0x7FFF + ((b >> 16) & 1)) >> 16);
        xo[c] = o;
    }
    __shared__ float sw[4];
    for (int off = 32; off; off >>= 1) s += __shfl_down(s, off);
    int wid = tid >> 6;
    if ((tid & 63) == 0) sw[wid] = s;
    __syncthreads();
    if (tid == 0) sq[row] = sw[0] + sw[1] + sw[2] + sw[3];
}

// ---------------------------------------------------------------------------
// Kernel 2: per-label two smallest indices + count (64 labels)
// ---------------------------------------------------------------------------
__global__ __launch_bounds__(256) void labelinfo_kernel(const int* __restrict__ targets,
                                                        int* __restrict__ f1,
                                                        int* __restrict__ f2,
                                                        int* __restrict__ lcnt, int N) {
    int lbl = blockIdx.x;
    int tid = threadIdx.x;
    int a1 = INT_MAX, a2 = INT_MAX, c = 0;
    for (int j = tid; j < N; j += 256) {
        if (targets[j] == lbl) {
            ++c;
            if (j < a1) { a2 = a1; a1 = j; }
            else if (j < a2) a2 = j;
        }
    }
    __shared__ int s1[4], s2[4], sc[4];
    for (int off = 32; off; off >>= 1) {
        int b1 = __shfl_down(a1, off), b2 = __shfl_down(a2, off), bc = __shfl_down(c, off);
        int m1 = min(a1, b1);
        int m2 = min(max(a1, b1), min(a2, b2));
        a1 = m1; a2 = m2; c += bc;
    }
    int wid = tid >> 6;
    if ((tid & 63) == 0) { s1[wid] = a1; s2[wid] = a2; sc[wid] = c; }
    __syncthreads();
    if (tid == 0) {
        int r1 = s1[0], r2 = s2[0], rc = sc[0];
        for (int w = 1; w < 4; ++w) {
            int m1 = min(r1, s1[w]);
            int m2 = min(max(r1, s1[w]), min(r2, s2[w]));
            r1 = m1; r2 = m2; rc += sc[w];
        }
        f1[lbl] = r1; f2[lbl] = r2; lcnt[lbl] = rc;
    }
}

// ---------------------------------------------------------------------------
// Kernel 3: bf16 MFMA GEMM, upper-triangle tiles, prefetch-early double-
// buffered staging (issue next K-step's global_load_lds BEFORE computing the
// current step; the __syncthreads drain then hits loads that had the whole
// MFMA phase to land). Candidates ballot-compacted to LDS, bulk-written.
// ---------------------------------------------------------------------------
#define GBM 128
#define GBK 32
__global__ __launch_bounds__(256) void distgemm_mfma(const ushort* __restrict__ Xb,
                                                     const float* __restrict__ sq,
                                                     float2* __restrict__ tileList,
                                                     int* __restrict__ tileCnt,
                                                     int* __restrict__ needFB,
                                                     int N, int D) {
    if (blockIdx.x < blockIdx.y) return;   // upper triangle only
    __shared__ ushort As[2][GBM * GBK];    // 2 x 8 KB
    __shared__ ushort Bs[2][GBM * GBK];    // 2 x 8 KB
    __shared__ float2 tlist[TCAP];         // 8 KB
    __shared__ int s_cnt;

    int tid = threadIdx.x;
    int lane = tid & 63;
    int wave = tid >> 6;
    int waveR = wave >> 1;
    int waveC = wave & 1;

    int rowBase = blockIdx.y * GBM;
    int colBase = blockIdx.x * GBM;

    if (tid == 0) s_cnt = 0;

    f32x4 acc[4][4];
#pragma unroll
    for (int m = 0; m < 4; ++m)
#pragma unroll
        for (int n2 = 0; n2 < 4; ++n2) {
            f32x4 z = {0.f, 0.f, 0.f, 0.f};
            acc[m][n2] = z;
        }

    // per-wave staging: 2 chunks of A + 2 of B (16B/lane each) per K-step
    auto STAGE = [&](int buf, int k0) {
#pragma unroll
        for (int p = 0; p < 2; ++p) {
            int c = wave + 4 * p;                 // 0..7
            int byteoff = c * 1024 + lane * 16;
            int r  = byteoff >> 6;
            int kk = (byteoff & 63) >> 1;
            const ushort* gA = Xb + (size_t)(rowBase + r) * D + k0 + kk;
            const ushort* gB = Xb + (size_t)(colBase + r) * D + k0 + kk;
            __builtin_amdgcn_global_load_lds(GLB_PTR(gA), LDS_PTR(&As[buf][c * 512]), 16, 0, 0);
            __builtin_amdgcn_global_load_lds(GLB_PTR(gB), LDS_PTR(&Bs[buf][c * 512]), 16, 0, 0);
        }
    };

    int nt = D / GBK;   // 32
    STAGE(0, 0);
    __syncthreads();    // buffer 0 staged

    int cur = 0;
    for (int t = 0; t < nt; ++t) {
        if (t + 1 < nt) STAGE(cur ^ 1, (t + 1) * GBK);   // issue-early prefetch

        bf16x8 aF[4], bF[4];
        int chunk = (lane >> 4) * 8;
#pragma unroll
        for (int m = 0; m < 4; ++m) {
            int rl = waveR * 64 + m * 16 + (lane & 15);
            aF[m] = *reinterpret_cast<const bf16x8*>(&As[cur][rl * GBK + chunk]);
        }
#pragma unroll
        for (int n2 = 0; n2 < 4; ++n2) {
            int rl = waveC * 64 + n2 * 16 + (lane & 15);
            bF[n2] = *reinterpret_cast<const bf16x8*>(&Bs[cur][rl * GBK + chunk]);
        }
#pragma unroll
        for (int m = 0; m < 4; ++m)
#pragma unroll
            for (int n2 = 0; n2 < 4; ++n2)
                acc[m][n2] = __builtin_amdgcn_mfma_f32_16x16x32_bf16(aF[m], bF[n2], acc[m][n2], 0, 0, 0);

        __syncthreads();   // next buffer staged (loads had whole MFMA phase);
        cur ^= 1;          // current buffer free to overwrite
    }

    // epilogue: ballot-compact candidates into LDS tile list (no global atomics)
    int cr = (lane >> 4) * 4;
    int cc = lane & 15;
    unsigned long long lmask_lt = (1ull << lane) - 1ull;
#pragma unroll
    for (int m = 0; m < 4; ++m) {
#pragma unroll
        for (int n2 = 0; n2 < 4; ++n2) {
            int gcol = colBase + waveC * 64 + n2 * 16 + cc;
            float sqc = sq[gcol];
#pragma unroll
            for (int r = 0; r < 4; ++r) {
                int grow = rowBase + waveR * 64 + m * 16 + cr + r;
                float v = sq[grow] + sqc - 2.0f * acc[m][n2][r];
                bool pred = (v < P0SQ) && (grow != gcol);
                unsigned long long mask = __ballot(pred);
                if (mask) {
                    int leader = __ffsll((long long)mask) - 1;
                    int tot = __popcll(mask);
                    int base = 0;
                    if (lane == leader) base = atomicAdd(&s_cnt, tot);
                    base = __shfl(base, leader);
                    if (pred) {
                        int idx = base + __popcll(mask & lmask_lt);
                        if (idx < TCAP) {
                            float d = sqrtf(fmaxf(v, 1e-12f));
                            uint32_t pk = ((uint32_t)grow << 12) | (uint32_t)gcol;
                            float2 e; e.x = d; e.y = __builtin_bit_cast(float, pk);
                            tlist[idx] = e;
                        }
                    }
                }
            }
        }
    }
    __syncthreads();

    int cnt = s_cnt;
    int tileId = blockIdx.y * gridDim.x + blockIdx.x;
    int wr = min(cnt, TCAP);
    for (int e = tid; e < wr; e += 256)
        tileList[(size_t)tileId * TCAP + e] = tlist[e];
    if (tid == 0) tileCnt[tileId] = cnt;
    if (cnt > TCAP) {   // astronomically unlikely; exact fallback covers it
        if (tid < GBM) needFB[rowBase + tid] = 1;
        else needFB[colBase + tid - GBM] = 1;
    }
}

// ---------------------------------------------------------------------------
// Kernel 4: binning — scatter tile lists into per-row candidate lists.
// ---------------------------------------------------------------------------
__global__ __launch_bounds__(256) void bin_kernel(const float2* __restrict__ tileList,
                                                  const int* __restrict__ tileCnt,
                                                  float2* __restrict__ cand,
                                                  int* __restrict__ cntArr) {
    int bx = blockIdx.x, by = blockIdx.y;
    if (bx < by) return;
    int t = by * gridDim.x + bx;
    int cnt = min(tileCnt[t], TCAP);
    bool diag = (bx == by);
    for (int e = threadIdx.x; e < cnt; e += 256) {
        float2 v = tileList[(size_t)t * TCAP + e];
        uint32_t pk = __builtin_bit_cast(uint32_t, v.y);
        int i = (int)(pk >> 12), j = (int)(pk & 4095u);
        int p = atomicAdd(&cntArr[i], 1);
        if (p < CAP) {
            float2 e1; e1.x = v.x; e1.y = __builtin_bit_cast(float, j);
            cand[(size_t)i * CAP + p] = e1;
        }
        if (!diag) {
            int q = atomicAdd(&cntArr[j], 1);
            if (q < CAP) {
                float2 e2; e2.x = v.x; e2.y = __builtin_bit_cast(float, i);
                cand[(size_t)j * CAP + q] = e2;
            }
        }
    }
}

// ---------------------------------------------------------------------------
// Kernel 5: per-row finalize from candidate lists. One WAVE per row (4/block).
// ---------------------------------------------------------------------------
__global__ __launch_bounds__(256) void rowfinal_kernel(const float2* __restrict__ cand,
                                                       const int* __restrict__ cntArr,
                                                       const int* __restrict__ targets,
                                                       const ushort* __restrict__ Xb,
                                                       const float* __restrict__ sq,
                                                       const int* __restrict__ f1,
                                                       const int* __restrict__ f2,
                                                       const int* __restrict__ lcnt,
                                                       int* __restrict__ needFB,
                                                       float* __restrict__ rowLoss,
                                                       int N, int D) {
    __shared__ float dbuf[4][CAP];
    int tid = threadIdx.x, lane = tid & 63, w = tid >> 6;
    int row = blockIdx.x * 4 + w;
    int ti = targets[row];
    int lc = lcnt[ti];
    bool validRow = (lc >= 2) && (lc < N);
    int cnt = cntArr[row];
    bool fb = (cnt < KSEL + 1) || (cnt > CAP);
    int lim = fb ? 0 : cnt;

    float ed[4]; int ej[4];
#pragma unroll
    for (int s = 0; s < 4; ++s) {
        int idx = lane + s * 64;
        bool in = (!fb) && (idx < cnt);
        if (in) {
            float2 e = cand[(size_t)row * CAP + idx];
            ed[s] = e.x; ej[s] = __builtin_bit_cast(int, e.y);
            dbuf[w][idx] = e.x;
        } else { ed[s] = BIGV; ej[s] = -1; }
    }
    __syncthreads();

    // exact rank: thr = value at rank KSEL (0-based) among candidates
    int rlo[4] = {0, 0, 0, 0}, req[4] = {0, 0, 0, 0};
    for (int q = 0; q < lim; ++q) {
        float u = dbuf[w][q];
#pragma unroll
        for (int s = 0; s < 4; ++s) {
            rlo[s] += (u < ed[s]);
            req[s] += (u == ed[s]);
        }
    }
    float thrc = BIGV;
#pragma unroll
    for (int s = 0; s < 4; ++s)
        if (ej[s] >= 0 && rlo[s] <= KSEL && KSEL < rlo[s] + req[s]) thrc = fminf(thrc, ed[s]);
    for (int off = 32; off; off >>= 1) thrc = fminf(thrc, __shfl_down(thrc, off));
    float thr = __shfl(thrc, 0);

    // masked sums over candidates (below-thr set fully contained in list)
    float posS = 0.f, negS = 0.f;
    int apb = 0;
#pragma unroll
    for (int s = 0; s < 4; ++s) {
        if (ej[s] >= 0 && ed[s] < thr) {
            bool same = (targets[ej[s]] == ti);
            float e = expf(ALPHA * (1.0f - ed[s]));
            if (same) { posS += e; apb = 1; }
            else negS += e;
        }
    }
    for (int off = 32; off; off >>= 1) {
        posS += __shfl_down(posS, off);
        negS += __shfl_down(negS, off);
        apb = max(apb, __shfl_down(apb, off));
    }

    // first-positive fallback distance (bf16 dot, fp32 accum)
    int fp = 0;
    float dot = 0.f;
    if (validRow) {
        fp = (row == f1[ti]) ? f2[ti] : f1[ti];
        const ushort* xr = Xb + (size_t)row * D;
        const ushort* xf = Xb + (size_t)fp * D;
        for (int c = lane; c < D / 4; c += 64) {
            ushort4 a = *reinterpret_cast<const ushort4*>(xr + (size_t)c * 4);
            ushort4 b = *reinterpret_cast<const ushort4*>(xf + (size_t)c * 4);
            dot += bfval(a.x) * bfval(b.x) + bfval(a.y) * bfval(b.y)
                 + bfval(a.z) * bfval(b.z) + bfval(a.w) * bfval(b.w);
        }
    }
    for (int off = 32; off; off >>= 1) dot += __shfl_down(dot, off);

    if (lane == 0) {
        if (fb) {
            needFB[row] = 1;
        } else if (!validRow) {
            rowLoss[row] = BIGV;
        } else {
            float fbD = sqrtf(fmaxf(sq[row] + sq[fp] - 2.0f * dot, 1e-12f));
            float posLogit = apb ? posS : expf(ALPHA * (1.0f - fbD));
            rowLoss[row] = -logf(posLogit / (posLogit + negS));
        }
    }
}

// ---------------------------------------------------------------------------
// Kernel 6: exact fallback (full-row recompute). Expected zero work.
// ---------------------------------------------------------------------------
__global__ __launch_bounds__(256) void fallback_kernel(const ushort* __restrict__ Xb,
                                                       const float* __restrict__ sq,
                                                       const int* __restrict__ targets,
                                                       const int* __restrict__ needFB,
                                                       const int* __restrict__ f1,
                                                       const int* __restrict__ f2,
                                                       const int* __restrict__ lcnt,
                                                       float* __restrict__ rowLoss,
                                                       int N, int D) {
    int row = blockIdx.x;
    if (!needFB[row]) return;

    __shared__ float xrow[1024];
    __shared__ float rowD[NMAX];
    __shared__ float sF[4];
    __shared__ int sI[4];
    int tid = threadIdx.x;

    for (int k = tid; k < D; k += 256) xrow[k] = bfval(Xb[(size_t)row * D + k]);
    __syncthreads();

    for (int j = tid; j < N; j += 256) {
        float dot = 0.f;
        const ushort* xj = Xb + (size_t)j * D;
        for (int k = 0; k < D; ++k) dot += xrow[k] * bfval(xj[k]);
        rowD[j] = (j == row) ? BIGV
                             : sqrtf(fmaxf(sq[row] + sq[j] - 2.0f * dot, 1e-12f));
    }
    __syncthreads();

    uint32_t lo = 0, hi = 0x40800000u;
    while (lo < hi) {
        uint32_t mid = (lo + hi) >> 1;
        float mv = __builtin_bit_cast(float, mid);
        int c = 0;
        for (int j = tid; j < N; j += 256) c += (rowD[j] <= mv);
        c = blockReduceSumI(c, sI);
        if (c >= KSEL + 1) hi = mid; else lo = mid + 1;
    }
    float thr = __builtin_bit_cast(float, hi);

    int ti = targets[row];
    int lc = lcnt[ti];
    bool validRow = (lc >= 2) && (lc < N);

    float posS = 0.f, negS = 0.f;
    int apb = 0;
    for (int j = tid; j < N; j += 256) {
        if (j == row) continue;
        float d = rowD[j];
        bool same = (targets[j] == ti);
        if (d < thr) {
            float e = expf(ALPHA * (1.0f - d));
            if (same) { posS += e; apb = 1; }
            else negS += e;
        }
    }
    posS = blockReduceSumF(posS, sF);
    negS = blockReduceSumF(negS, sF);
    apb = blockReduceMaxI(apb, sI);

    if (tid == 0) {
        if (!validRow) { rowLoss[row] = BIGV; return; }
        int fp = (row == f1[ti]) ? f2[ti] : f1[ti];
        float posLogit = apb ? posS : expf(ALPHA * (1.0f - rowD[fp]));
        rowLoss[row] = -logf(posLogit / (posLogit + negS));
    }
}

// ---------------------------------------------------------------------------
// Kernel 7: single-block reduction over rowLoss -> out[4]
// ---------------------------------------------------------------------------
__global__ __launch_bounds__(256) void reduce_kernel(const float* __restrict__ rowLoss,
                                                     float* __restrict__ out, int N) {
    __shared__ float sF[4];
    __shared__ int sI[4];
    int tid = threadIdx.x;
    float sumL = 0.f;
    int nValid = 0, nAcc = 0;
    for (int j = tid; j < N; j += 256) {
        float L = rowLoss[j];
        if (L != BIGV) {
            sumL += L;
            ++nValid;
            if (L < 0.6f) ++nAcc;
        }
    }
    sumL = blockReduceSumF(sumL, sF);
    nValid = blockReduceSumI(nValid, sI);
    nAcc = blockReduceSumI(nAcc, sI);
    if (tid == 0) {
        out[0] = (nValid > 0) ? sumL / (float)nValid : 0.f;
        out[1] = (float)nAcc / (float)N;
        out[2] = 0.f;
        out[3] = 0.f;
    }
}

// ---------------------------------------------------------------------------
extern "C" void kernel_launch(void* const* d_in, const int* in_sizes, int n_in,
                              void* d_out, int out_size, void* d_ws, size_t ws_size,
                              hipStream_t stream) {
    const float* X = (const float*)d_in[0];
    const int* targets = (const int*)d_in[1];
    float* out = (float*)d_out;

    int N = in_sizes[1];             // 4096
    int D = in_sizes[0] / N;         // 1024
    int tiles = N / GBM;             // 32

    // 8B-aligned float2 arrays first
    float2* cand     = (float2*)d_ws;                          // N*CAP f2      (7.3 MB)
    float2* tileList = cand + (size_t)N * CAP;                 // tiles^2*TCAP  (8.4 MB)
    float*  sq       = (float*)(tileList + (size_t)tiles * tiles * TCAP);
    float*  rowLoss  = sq + N;
    int*    cntArr   = (int*)(rowLoss + N);
    int*    needFB   = cntArr + N;
    int*    tileCnt  = needFB + N;                             // tiles^2 i32
    int*    f1       = tileCnt + tiles * tiles;
    int*    f2       = f1 + 64;
    int*    lcnt     = f2 + 64;
    ushort* Xb       = (ushort*)(lcnt + 64 + 64);              // N*D bf16 (8 MB)

    hipMemsetAsync(cntArr, 0, N * sizeof(int), stream);
    hipMemsetAsync(needFB, 0, N * sizeof(int), stream);

    prep_kernel<<<N, 256, 0, stream>>>(X, Xb, sq, D);
    labelinfo_kernel<<<64, 256, 0, stream>>>(targets, f1, f2, lcnt, N);

    dim3 grid(tiles, tiles);
    distgemm_mfma<<<grid, 256, 0, stream>>>(Xb, sq, tileList, tileCnt, needFB, N, D);

    bin_kernel<<<grid, 256, 0, stream>>>(tileList, tileCnt, cand, cntArr);

    rowfinal_kernel<<<N / 4, 256, 0, stream>>>(cand, cntArr, targets, Xb, sq,
                                               f1, f2, lcnt, needFB, rowLoss, N, D);

    fallback_kernel<<<N, 256, 0, stream>>>(Xb, sq, targets, needFB,
                                           f1, f2, lcnt, rowLoss, N, D);

    reduce_kernel<<<1, 256, 0, stream>>>(rowLoss, out, N);
}

// Round 9
// 144.158 us; speedup vs baseline: 1.2931x; 1.0266x over previous
//
#include <hip/hip_runtime.h>
#include <hip/hip_bf16.h>
#include <cfloat>
#include <climits>
#include <cstdint>

#define ALPHA 30.0f
#define KSEL 16          // threshold = sorted[:,16] (17th smallest off-diag)
#define P0 1.368f        // candidate cutoff: E[cnt/row]≈82, P(cnt<17)~1e-13
#define P0SQ (P0 * P0)
#define CAP 224          // per-row candidate capacity (mean 82, +15 sigma)
#define TCAP 896         // per-tile candidate capacity (mean 330, +31 sigma)
#define BIGV 1e30f
#define NMAX 4096

typedef __attribute__((ext_vector_type(8))) short bf16x8;
typedef __attribute__((ext_vector_type(4))) float f32x4;

#define LDS_PTR(p) ((__attribute__((address_space(3))) uint32_t*)(p))
#define GLB_PTR(p) ((const __attribute__((address_space(1))) uint32_t*)(p))

__device__ inline float bfval(ushort u) {
    return __builtin_bit_cast(float, (uint32_t)u << 16);
}

// ---------------------------------------------------------------------------
// block reduce helpers (256 threads, 4 waves)
// ---------------------------------------------------------------------------
__device__ inline float blockReduceSumF(float v, float* s) {
    for (int off = 32; off; off >>= 1) v += __shfl_down(v, off);
    int tid = threadIdx.x, wid = tid >> 6;
    if ((tid & 63) == 0) s[wid] = v;
    __syncthreads();
    float r;
    if (tid == 0) { r = s[0] + s[1] + s[2] + s[3]; s[0] = r; }
    __syncthreads();
    r = s[0];
    __syncthreads();
    return r;
}

__device__ inline int blockReduceSumI(int v, int* s) {
    for (int off = 32; off; off >>= 1) v += __shfl_down(v, off);
    int tid = threadIdx.x, wid = tid >> 6;
    if ((tid & 63) == 0) s[wid] = v;
    __syncthreads();
    int r;
    if (tid == 0) { r = s[0] + s[1] + s[2] + s[3]; s[0] = r; }
    __syncthreads();
    r = s[0];
    __syncthreads();
    return r;
}

__device__ inline int blockReduceMaxI(int v, int* s) {
    for (int off = 32; off; off >>= 1) v = max(v, __shfl_down(v, off));
    int tid = threadIdx.x, wid = tid >> 6;
    if ((tid & 63) == 0) s[wid] = v;
    __syncthreads();
    int r;
    if (tid == 0) { r = max(max(s[0], s[1]), max(s[2], s[3])); s[0] = r; }
    __syncthreads();
    r = s[0];
    __syncthreads();
    return r;
}

// ---------------------------------------------------------------------------
// Kernel 1: fused fp32->bf16 (RNE) + row sq-norm; blocks >= N do labelinfo.
// ---------------------------------------------------------------------------
__global__ __launch_bounds__(256) void prep_kernel(const float* __restrict__ X,
                                                   ushort* __restrict__ Xb,
                                                   float* __restrict__ sq,
                                                   const int* __restrict__ targets,
                                                   int* __restrict__ f1,
                                                   int* __restrict__ f2,
                                                   int* __restrict__ lcnt,
                                                   int D, int N) {
    __shared__ float sw[4];
    __shared__ int s1[4], s2[4], sc[4];
    int tid = threadIdx.x;
    int wid = tid >> 6;

    if (blockIdx.x >= (unsigned)N) {
        // ---- labelinfo: per-label two smallest indices + count ----
        int lbl = blockIdx.x - N;
        int a1 = INT_MAX, a2 = INT_MAX, c = 0;
        for (int j = tid; j < N; j += 256) {
            if (targets[j] == lbl) {
                ++c;
                if (j < a1) { a2 = a1; a1 = j; }
                else if (j < a2) a2 = j;
            }
        }
        for (int off = 32; off; off >>= 1) {
            int b1 = __shfl_down(a1, off), b2 = __shfl_down(a2, off), bc = __shfl_down(c, off);
            int m1 = min(a1, b1);
            int m2 = min(max(a1, b1), min(a2, b2));
            a1 = m1; a2 = m2; c += bc;
        }
        if ((tid & 63) == 0) { s1[wid] = a1; s2[wid] = a2; sc[wid] = c; }
        __syncthreads();
        if (tid == 0) {
            int r1 = s1[0], r2 = s2[0], rc = sc[0];
            for (int w = 1; w < 4; ++w) {
                int m1 = min(r1, s1[w]);
                int m2 = min(max(r1, s1[w]), min(r2, s2[w]));
                r1 = m1; r2 = m2; rc += sc[w];
            }
            f1[lbl] = r1; f2[lbl] = r2; lcnt[lbl] = rc;
        }
        return;
    }

    int row = blockIdx.x;
    const float4* xr = reinterpret_cast<const float4*>(X + (size_t)row * D);
    ushort4* xo = reinterpret_cast<ushort4*>(Xb + (size_t)row * D);
    float s = 0.f;
    for (int c = tid; c < D / 4; c += 256) {
        float4 v = xr[c];
        s += v.x * v.x + v.y * v.y + v.z * v.z + v.w * v.w;
        ushort4 o;
        uint32_t b;
        b = __builtin_bit_cast(uint32_t, v.x); o.x = (ushort)((b + 0x7FFF + ((b >> 16) & 1)) >> 16);
        b = __builtin_bit_cast(uint32_t, v.y); o.y = (ushort)((b + 0x7FFF + ((b >> 16) & 1)) >> 16);
        b = __builtin_bit_cast(uint32_t, v.z); o.z = (ushort)((b + 0x7FFF + ((b >> 16) & 1)) >> 16);
        b = __builtin_bit_cast(uint32_t, v.w); o.w = (ushort)((b + 0x7FFF + ((b >> 16) & 1)) >> 16);
        xo[c] = o;
    }
    for (int off = 32; off; off >>= 1) s += __shfl_down(s, off);
    if ((tid & 63) == 0) sw[wid] = s;
    __syncthreads();
    if (tid == 0) sq[row] = sw[0] + sw[1] + sw[2] + sw[3];
}

// ---------------------------------------------------------------------------
// Kernel 2: bf16 MFMA GEMM, FULL grid (1024 blocks = 4/CU), XCD-swizzled,
// prefetch-early double-buffered staging, NO dist matrix. Candidates
// (v < P0^2, off-diag) ballot-compacted to LDS, bulk-written; ROW-side push
// only — the transposed tile supplies the mirror record.
// ---------------------------------------------------------------------------
#define GBM 128
#define GBK 32
__global__ __launch_bounds__(256) void distgemm_mfma(const ushort* __restrict__ Xb,
                                                     const float* __restrict__ sq,
                                                     float2* __restrict__ tileList,
                                                     int* __restrict__ tileCnt,
                                                     int* __restrict__ needFB,
                                                     int N, int D) {
    __shared__ ushort As[2][GBM * GBK];    // 2 x 8 KB
    __shared__ ushort Bs[2][GBM * GBK];    // 2 x 8 KB
    __shared__ float2 tlist[TCAP];         // 7 KB
    __shared__ int s_cnt;

    // XCD-aware swizzle: 1024 blocks, 8 XCDs -> each XCD gets 128 consecutive
    // wgids (4 contiguous row-panels) for A-panel L2 reuse.
    int wg = blockIdx.x;
    int wgid = (wg & 7) * 128 + (wg >> 3);
    int by = wgid >> 5, bx = wgid & 31;

    int tid = threadIdx.x;
    int lane = tid & 63;
    int wave = tid >> 6;
    int waveR = wave >> 1;
    int waveC = wave & 1;

    int rowBase = by * GBM;
    int colBase = bx * GBM;

    if (tid == 0) s_cnt = 0;

    f32x4 acc[4][4];
#pragma unroll
    for (int m = 0; m < 4; ++m)
#pragma unroll
        for (int n2 = 0; n2 < 4; ++n2) {
            f32x4 z = {0.f, 0.f, 0.f, 0.f};
            acc[m][n2] = z;
        }

    auto STAGE = [&](int buf, int k0) {
#pragma unroll
        for (int p = 0; p < 2; ++p) {
            int c = wave + 4 * p;                 // 0..7
            int byteoff = c * 1024 + lane * 16;
            int r  = byteoff >> 6;
            int kk = (byteoff & 63) >> 1;
            const ushort* gA = Xb + (size_t)(rowBase + r) * D + k0 + kk;
            const ushort* gB = Xb + (size_t)(colBase + r) * D + k0 + kk;
            __builtin_amdgcn_global_load_lds(GLB_PTR(gA), LDS_PTR(&As[buf][c * 512]), 16, 0, 0);
            __builtin_amdgcn_global_load_lds(GLB_PTR(gB), LDS_PTR(&Bs[buf][c * 512]), 16, 0, 0);
        }
    };

    int nt = D / GBK;   // 32
    STAGE(0, 0);
    __syncthreads();

    int cur = 0;
    for (int t = 0; t < nt; ++t) {
        if (t + 1 < nt) STAGE(cur ^ 1, (t + 1) * GBK);

        bf16x8 aF[4], bF[4];
        int chunk = (lane >> 4) * 8;
#pragma unroll
        for (int m = 0; m < 4; ++m) {
            int rl = waveR * 64 + m * 16 + (lane & 15);
            aF[m] = *reinterpret_cast<const bf16x8*>(&As[cur][rl * GBK + chunk]);
        }
#pragma unroll
        for (int n2 = 0; n2 < 4; ++n2) {
            int rl = waveC * 64 + n2 * 16 + (lane & 15);
            bF[n2] = *reinterpret_cast<const bf16x8*>(&Bs[cur][rl * GBK + chunk]);
        }
#pragma unroll
        for (int m = 0; m < 4; ++m)
#pragma unroll
            for (int n2 = 0; n2 < 4; ++n2)
                acc[m][n2] = __builtin_amdgcn_mfma_f32_16x16x32_bf16(aF[m], bF[n2], acc[m][n2], 0, 0, 0);

        __syncthreads();
        cur ^= 1;
    }

    // epilogue: ballot-compact candidates into LDS tile list (no global atomics)
    int cr = (lane >> 4) * 4;
    int cc = lane & 15;
    unsigned long long lmask_lt = (1ull << lane) - 1ull;
#pragma unroll
    for (int m = 0; m < 4; ++m) {
#pragma unroll
        for (int n2 = 0; n2 < 4; ++n2) {
            int gcol = colBase + waveC * 64 + n2 * 16 + cc;
            float sqc = sq[gcol];
#pragma unroll
            for (int r = 0; r < 4; ++r) {
                int grow = rowBase + waveR * 64 + m * 16 + cr + r;
                float v = sq[grow] + sqc - 2.0f * acc[m][n2][r];
                bool pred = (v < P0SQ) && (grow != gcol);
                unsigned long long mask = __ballot(pred);
                if (mask) {
                    int leader = __ffsll((long long)mask) - 1;
                    int tot = __popcll(mask);
                    int base = 0;
                    if (lane == leader) base = atomicAdd(&s_cnt, tot);
                    base = __shfl(base, leader);
                    if (pred) {
                        int idx = base + __popcll(mask & lmask_lt);
                        if (idx < TCAP) {
                            float d = sqrtf(fmaxf(v, 1e-12f));
                            uint32_t pk = ((uint32_t)grow << 12) | (uint32_t)gcol;
                            float2 e; e.x = d; e.y = __builtin_bit_cast(float, pk);
                            tlist[idx] = e;
                        }
                    }
                }
            }
        }
    }
    __syncthreads();

    int cnt = s_cnt;
    int wr = min(cnt, TCAP);
    for (int e = tid; e < wr; e += 256)
        tileList[(size_t)wgid * TCAP + e] = tlist[e];
    if (tid == 0) tileCnt[wgid] = cnt;
    if (cnt > TCAP && tid < GBM)   // astronomically unlikely; rows lose records
        needFB[rowBase + tid] = 1;
}

// ---------------------------------------------------------------------------
// Kernel 3: binning — scatter tile lists into per-row candidate lists.
// One push per record (row side); high occupancy hides atomic latency.
// ---------------------------------------------------------------------------
__global__ __launch_bounds__(256) void bin_kernel(const float2* __restrict__ tileList,
                                                  const int* __restrict__ tileCnt,
                                                  float2* __restrict__ cand,
                                                  int* __restrict__ cntArr) {
    int t = blockIdx.x;
    int cnt = min(tileCnt[t], TCAP);
    for (int e = threadIdx.x; e < cnt; e += 256) {
        float2 v = tileList[(size_t)t * TCAP + e];
        uint32_t pk = __builtin_bit_cast(uint32_t, v.y);
        int i = (int)(pk >> 12), j = (int)(pk & 4095u);
        int p = atomicAdd(&cntArr[i], 1);
        if (p < CAP) {
            float2 e1; e1.x = v.x; e1.y = __builtin_bit_cast(float, j);
            cand[(size_t)i * CAP + p] = e1;
        }
    }
}

// ---------------------------------------------------------------------------
// Kernel 4: per-row finalize from candidate lists. One WAVE per row (4/block).
// ---------------------------------------------------------------------------
__global__ __launch_bounds__(256) void rowfinal_kernel(const float2* __restrict__ cand,
                                                       const int* __restrict__ cntArr,
                                                       const int* __restrict__ targets,
                                                       const ushort* __restrict__ Xb,
                                                       const float* __restrict__ sq,
                                                       const int* __restrict__ f1,
                                                       const int* __restrict__ f2,
                                                       const int* __restrict__ lcnt,
                                                       int* __restrict__ needFB,
                                                       float* __restrict__ rowLoss,
                                                       int N, int D) {
    __shared__ float dbuf[4][CAP];
    int tid = threadIdx.x, lane = tid & 63, w = tid >> 6;
    int row = blockIdx.x * 4 + w;
    int ti = targets[row];
    int lc = lcnt[ti];
    bool validRow = (lc >= 2) && (lc < N);
    int cnt = cntArr[row];
    bool fb = (cnt < KSEL + 1) || (cnt > CAP);
    int lim = fb ? 0 : cnt;

    float ed[4]; int ej[4];
#pragma unroll
    for (int s = 0; s < 4; ++s) {
        int idx = lane + s * 64;
        bool in = (!fb) && (idx < cnt);
        if (in) {
            float2 e = cand[(size_t)row * CAP + idx];
            ed[s] = e.x; ej[s] = __builtin_bit_cast(int, e.y);
            dbuf[w][idx] = e.x;
        } else { ed[s] = BIGV; ej[s] = -1; }
    }
    __syncthreads();

    // exact rank: thr = value at rank KSEL (0-based) among candidates
    int rlo[4] = {0, 0, 0, 0}, req[4] = {0, 0, 0, 0};
    for (int q = 0; q < lim; ++q) {
        float u = dbuf[w][q];
#pragma unroll
        for (int s = 0; s < 4; ++s) {
            rlo[s] += (u < ed[s]);
            req[s] += (u == ed[s]);
        }
    }
    float thrc = BIGV;
#pragma unroll
    for (int s = 0; s < 4; ++s)
        if (ej[s] >= 0 && rlo[s] <= KSEL && KSEL < rlo[s] + req[s]) thrc = fminf(thrc, ed[s]);
    for (int off = 32; off; off >>= 1) thrc = fminf(thrc, __shfl_down(thrc, off));
    float thr = __shfl(thrc, 0);

    // masked sums over candidates (below-thr set fully contained in list)
    float posS = 0.f, negS = 0.f;
    int apb = 0;
#pragma unroll
    for (int s = 0; s < 4; ++s) {
        if (ej[s] >= 0 && ed[s] < thr) {
            bool same = (targets[ej[s]] == ti);
            float e = expf(ALPHA * (1.0f - ed[s]));
            if (same) { posS += e; apb = 1; }
            else negS += e;
        }
    }
    for (int off = 32; off; off >>= 1) {
        posS += __shfl_down(posS, off);
        negS += __shfl_down(negS, off);
        apb = max(apb, __shfl_down(apb, off));
    }

    // first-positive fallback distance (bf16 dot, fp32 accum)
    int fp = 0;
    float dot = 0.f;
    if (validRow) {
        fp = (row == f1[ti]) ? f2[ti] : f1[ti];
        const ushort* xr = Xb + (size_t)row * D;
        const ushort* xf = Xb + (size_t)fp * D;
        for (int c = lane; c < D / 4; c += 64) {
            ushort4 a = *reinterpret_cast<const ushort4*>(xr + (size_t)c * 4);
            ushort4 b = *reinterpret_cast<const ushort4*>(xf + (size_t)c * 4);
            dot += bfval(a.x) * bfval(b.x) + bfval(a.y) * bfval(b.y)
                 + bfval(a.z) * bfval(b.z) + bfval(a.w) * bfval(b.w);
        }
    }
    for (int off = 32; off; off >>= 1) dot += __shfl_down(dot, off);

    if (lane == 0) {
        if (fb) {
            needFB[row] = 1;
        } else if (!validRow) {
            rowLoss[row] = BIGV;
        } else {
            float fbD = sqrtf(fmaxf(sq[row] + sq[fp] - 2.0f * dot, 1e-12f));
            float posLogit = apb ? posS : expf(ALPHA * (1.0f - fbD));
            rowLoss[row] = -logf(posLogit / (posLogit + negS));
        }
    }
}

// ---------------------------------------------------------------------------
// Kernel 5: exact fallback (full-row recompute). Expected zero work.
// ---------------------------------------------------------------------------
__global__ __launch_bounds__(256) void fallback_kernel(const ushort* __restrict__ Xb,
                                                       const float* __restrict__ sq,
                                                       const int* __restrict__ targets,
                                                       const int* __restrict__ needFB,
                                                       const int* __restrict__ f1,
                                                       const int* __restrict__ f2,
                                                       const int* __restrict__ lcnt,
                                                       float* __restrict__ rowLoss,
                                                       int N, int D) {
    int row = blockIdx.x;
    if (!needFB[row]) return;

    __shared__ float xrow[1024];
    __shared__ float rowD[NMAX];
    __shared__ float sF[4];
    __shared__ int sI[4];
    int tid = threadIdx.x;

    for (int k = tid; k < D; k += 256) xrow[k] = bfval(Xb[(size_t)row * D + k]);
    __syncthreads();

    for (int j = tid; j < N; j += 256) {
        float dot = 0.f;
        const ushort* xj = Xb + (size_t)j * D;
        for (int k = 0; k < D; ++k) dot += xrow[k] * bfval(xj[k]);
        rowD[j] = (j == row) ? BIGV
                             : sqrtf(fmaxf(sq[row] + sq[j] - 2.0f * dot, 1e-12f));
    }
    __syncthreads();

    uint32_t lo = 0, hi = 0x40800000u;
    while (lo < hi) {
        uint32_t mid = (lo + hi) >> 1;
        float mv = __builtin_bit_cast(float, mid);
        int c = 0;
        for (int j = tid; j < N; j += 256) c += (rowD[j] <= mv);
        c = blockReduceSumI(c, sI);
        if (c >= KSEL + 1) hi = mid; else lo = mid + 1;
    }
    float thr = __builtin_bit_cast(float, hi);

    int ti = targets[row];
    int lc = lcnt[ti];
    bool validRow = (lc >= 2) && (lc < N);

    float posS = 0.f, negS = 0.f;
    int apb = 0;
    for (int j = tid; j < N; j += 256) {
        if (j == row) continue;
        float d = rowD[j];
        bool same = (targets[j] == ti);
        if (d < thr) {
            float e = expf(ALPHA * (1.0f - d));
            if (same) { posS += e; apb = 1; }
            else negS += e;
        }
    }
    posS = blockReduceSumF(posS, sF);
    negS = blockReduceSumF(negS, sF);
    apb = blockReduceMaxI(apb, sI);

    if (tid == 0) {
        if (!validRow) { rowLoss[row] = BIGV; return; }
        int fp = (row == f1[ti]) ? f2[ti] : f1[ti];
        float posLogit = apb ? posS : expf(ALPHA * (1.0f - rowD[fp]));
        rowLoss[row] = -logf(posLogit / (posLogit + negS));
    }
}

// ---------------------------------------------------------------------------
// Kernel 6: single-block reduction over rowLoss -> out[4]
// ---------------------------------------------------------------------------
__global__ __launch_bounds__(256) void reduce_kernel(const float* __restrict__ rowLoss,
                                                     float* __restrict__ out, int N) {
    __shared__ float sF[4];
    __shared__ int sI[4];
    int tid = threadIdx.x;
    float sumL = 0.f;
    int nValid = 0, nAcc = 0;
    for (int j = tid; j < N; j += 256) {
        float L = rowLoss[j];
        if (L != BIGV) {
            sumL += L;
            ++nValid;
            if (L < 0.6f) ++nAcc;
        }
    }
    sumL = blockReduceSumF(sumL, sF);
    nValid = blockReduceSumI(nValid, sI);
    nAcc = blockReduceSumI(nAcc, sI);
    if (tid == 0) {
        out[0] = (nValid > 0) ? sumL / (float)nValid : 0.f;
        out[1] = (float)nAcc / (float)N;
        out[2] = 0.f;
        out[3] = 0.f;
    }
}

// ---------------------------------------------------------------------------
extern "C" void kernel_launch(void* const* d_in, const int* in_sizes, int n_in,
                              void* d_out, int out_size, void* d_ws, size_t ws_size,
                              hipStream_t stream) {
    const float* X = (const float*)d_in[0];
    const int* targets = (const int*)d_in[1];
    float* out = (float*)d_out;

    int N = in_sizes[1];             // 4096
    int D = in_sizes[0] / N;         // 1024
    int tiles = N / GBM;             // 32
    int nTiles = tiles * tiles;      // 1024

    // 8B-aligned float2 arrays first
    float2* cand     = (float2*)d_ws;                          // N*CAP f2      (7.3 MB)
    float2* tileList = cand + (size_t)N * CAP;                 // nTiles*TCAP   (7.3 MB)
    float*  sq       = (float*)(tileList + (size_t)nTiles * TCAP);
    float*  rowLoss  = sq + N;
    int*    cntArr   = (int*)(rowLoss + N);
    int*    needFB   = cntArr + N;
    int*    tileCnt  = needFB + N;                             // nTiles i32
    int*    f1       = tileCnt + nTiles;
    int*    f2       = f1 + 64;
    int*    lcnt     = f2 + 64;
    ushort* Xb       = (ushort*)(lcnt + 64 + 64);              // N*D bf16 (8 MB)

    hipMemsetAsync(cntArr, 0, N * sizeof(int), stream);
    hipMemsetAsync(needFB, 0, N * sizeof(int), stream);

    prep_kernel<<<N + 64, 256, 0, stream>>>(X, Xb, sq, targets, f1, f2, lcnt, D, N);

    distgemm_mfma<<<nTiles, 256, 0, stream>>>(Xb, sq, tileList, tileCnt, needFB, N, D);

    bin_kernel<<<nTiles, 256, 0, stream>>>(tileList, tileCnt, cand, cntArr);

    rowfinal_kernel<<<N / 4, 256, 0, stream>>>(cand, cntArr, targets, Xb, sq,
                                               f1, f2, lcnt, needFB, rowLoss, N, D);

    fallback_kernel<<<N, 256, 0, stream>>>(Xb, sq, targets, needFB,
                                           f1, f2, lcnt, rowLoss, N, D);

    reduce_kernel<<<1, 256, 0, stream>>>(rowLoss, out, N);
}